// Round 6
// baseline (294.720 us; speedup 1.0000x reference)
//
#include <hip/hip_runtime.h>
#include <math.h>

#define N_NODES 50000
#define N_EDGES 800000
#define ET (N_EDGES + N_NODES)   // with self-loops
#define FDIM 128
#define HEADS 4
#define HID 32
#define NCLS 8
#define NEG 0.2f
#define EPS_BN 1e-5f

#define BSH 6                                   // 64 nodes per bucket
#define NBUCK ((N_NODES + 63) >> BSH)           // 782
#define EPB 4096                                // edges per partition block

typedef __attribute__((ext_vector_type(8))) short short8;
typedef __attribute__((ext_vector_type(4))) float f32x4;

__device__ __forceinline__ float lrelu(float e) { return e > 0.f ? e : NEG * e; }
__device__ __forceinline__ float bflo(unsigned u) { return __uint_as_float(u << 16); }
__device__ __forceinline__ float bfhi(unsigned u) { return __uint_as_float(u & 0xffff0000u); }
__device__ __forceinline__ unsigned f2bf(float f) {           // RNE round to bf16 bits
    unsigned b = __float_as_uint(f);
    return (b + 0x7fffu + ((b >> 16) & 1u)) >> 16;
}

// exclusive scan of bhist[NBUCK] into bloc[NBUCK] using stmp[256]; all 256 threads.
__device__ __forceinline__ void scan_bhist(const int* __restrict__ bhist,
                                           int* bloc, int* stmp) {
    int t = threadIdx.x;
    int idx = t * 4;
    int v0 = (idx     < NBUCK) ? bhist[idx]     : 0;
    int v1 = (idx + 1 < NBUCK) ? bhist[idx + 1] : 0;
    int v2 = (idx + 2 < NBUCK) ? bhist[idx + 2] : 0;
    int v3 = (idx + 3 < NBUCK) ? bhist[idx + 3] : 0;
    int sum = v0 + v1 + v2 + v3;
    stmp[t] = sum;
    __syncthreads();
    for (int off = 1; off < 256; off <<= 1) {
        int x = (t >= off) ? stmp[t - off] : 0;
        __syncthreads();
        stmp[t] += x;
        __syncthreads();
    }
    int run = stmp[t] - sum;
    if (idx     < NBUCK) bloc[idx]     = run; run += v0;
    if (idx + 1 < NBUCK) bloc[idx + 1] = run; run += v1;
    if (idx + 2 < NBUCK) bloc[idx + 2] = run; run += v2;
    if (idx + 3 < NBUCK) bloc[idx + 3] = run;
    __syncthreads();
}

// ---------------- fused K1: x->bf16 cast + W0/W1 fragment packing + bucket histogram ----------------

#define CAST_B 3125   // 50000*128/8/256
#define PACK_B 64     // 16384/256
#define PB ((ET + EPB - 1) / EPB)   // 208

__global__ __launch_bounds__(256) void prep_hist(
        const float* __restrict__ x, unsigned short* __restrict__ xb,
        const float* __restrict__ W0, unsigned short* __restrict__ W0p,
        const float* __restrict__ W1, unsigned short* __restrict__ W1p,
        const int* __restrict__ ei, int* __restrict__ bhist) {
    __shared__ unsigned h[NBUCK];
    int b = blockIdx.x, tid = threadIdx.x;
    if (b < CAST_B) {
        int i = b * 256 + tid;
        const float4* p = (const float4*)x + (size_t)i * 2;
        float4 a = p[0], c = p[1];
        uint4 o;
        o.x = f2bf(a.x) | (f2bf(a.y) << 16);
        o.y = f2bf(a.z) | (f2bf(a.w) << 16);
        o.z = f2bf(c.x) | (f2bf(c.y) << 16);
        o.w = f2bf(c.z) | (f2bf(c.w) << 16);
        ((uint4*)xb)[i] = o;
    } else if (b < CAST_B + 2 * PACK_B) {
        int pb = b - CAST_B;
        const float* W = (pb < PACK_B) ? W0 : W1;
        unsigned short* Wp = (pb < PACK_B) ? W0p : W1p;
        int o = (pb & (PACK_B - 1)) * 256 + tid;
        int j = o & 7, lane = (o >> 3) & 63, kc = (o >> 9) & 3, t = o >> 11;
        int k = kc * 32 + ((lane >> 4) << 3) + j;
        int n = t * 16 + (lane & 15);
        Wp[o] = (unsigned short)f2bf(W[k * 128 + n]);
    } else {
        int blk = b - (CAST_B + 2 * PACK_B);
        int e0 = blk * EPB;
        for (int i = tid; i < NBUCK; i += 256) h[i] = 0;
        __syncthreads();
        #pragma unroll
        for (int k = 0; k < EPB / 256; k++) {
            int e = e0 + k * 256 + tid;
            if (e < ET) {
                int d = (e < N_EDGES) ? ei[N_EDGES + e] : (e - N_EDGES);
                atomicAdd(&h[d >> BSH], 1u);
            }
        }
        __syncthreads();
        for (int i = tid; i < NBUCK; i += 256)
            if (h[i]) atomicAdd(&bhist[i], (int)h[i]);
    }
}

// ------- shared gemm body: fused MFMA GEMM (64 x 128 @ 128 x 128) + bf16 h-store + attn coeffs -------

__device__ __forceinline__ void gemm_attn_body(
        float* tiles, int gb,
        const unsigned short* __restrict__ Ab, const unsigned short* __restrict__ Wp,
        const float* __restrict__ att_s, const float* __restrict__ att_d,
        unsigned short* __restrict__ Hb, float* __restrict__ asn, float* __restrict__ adn,
        int M) {
    int tid = threadIdx.x;
    int wv = tid >> 6, lane = tid & 63;
    int base = gb * 64;
    int mrow = base + wv * 16 + (lane & 15);
    if (mrow >= M) mrow = M - 1;
    int koff = (lane >> 4) * 8;

    f32x4 acc[8];
    #pragma unroll
    for (int t = 0; t < 8; t++) acc[t] = (f32x4){0.f, 0.f, 0.f, 0.f};

    #pragma unroll
    for (int kc = 0; kc < 4; kc++) {
        short8 a = *(const short8*)(Ab + (size_t)mrow * 128 + kc * 32 + koff);
        #pragma unroll
        for (int t = 0; t < 8; t++) {
            short8 bfr = *(const short8*)(Wp + (((t * 4 + kc) * 64 + lane) << 3));
            acc[t] = __builtin_amdgcn_mfma_f32_16x16x32_bf16(a, bfr, acc[t], 0, 0, 0);
        }
    }

    int rbase = wv * 16 + (lane >> 4) * 4;
    int col = lane & 15;
    #pragma unroll
    for (int t = 0; t < 8; t++)
        #pragma unroll
        for (int r = 0; r < 4; r++)
            tiles[(rbase + r) * 132 + t * 16 + col] = acc[t][r];
    __syncthreads();

    #pragma unroll
    for (int it = 0; it < 4; it++) {
        int u = tid + it * 256;
        int rl = u >> 4, cg = u & 15;
        int row = base + rl;
        if (row < M) {
            const float* p = tiles + rl * 132 + cg * 8;
            float4 v0 = *(const float4*)(p);
            float4 v1 = *(const float4*)(p + 4);
            uint4 o;
            o.x = f2bf(v0.x) | (f2bf(v0.y) << 16);
            o.y = f2bf(v0.z) | (f2bf(v0.w) << 16);
            o.z = f2bf(v1.x) | (f2bf(v1.y) << 16);
            o.w = f2bf(v1.z) | (f2bf(v1.w) << 16);
            *(uint4*)(Hb + (size_t)row * 128 + cg * 8) = o;
        }
    }

    {
        int rl = tid >> 2, hd = tid & 3;
        int row = base + rl;
        if (row < M) {
            const float* hrow = tiles + rl * 132 + hd * 32;
            const float* as = att_s + hd * 32;
            const float* ad = att_d + hd * 32;
            float ps = 0.f, pd = 0.f;
            #pragma unroll
            for (int i = 0; i < 8; i++) {
                float4 hv = *(const float4*)(hrow + i * 4);
                float4 sv = *(const float4*)(as + i * 4);
                float4 dv = *(const float4*)(ad + i * 4);
                ps += hv.x * sv.x + hv.y * sv.y + hv.z * sv.z + hv.w * sv.w;
                pd += hv.x * dv.x + hv.y * dv.y + hv.z * dv.z + hv.w * dv.w;
            }
            asn[row * 4 + hd] = ps;
            adn[row * 4 + hd] = pd;
        }
    }
}

// ---------------- fused K2: radix partition (blocks [0,PB)) + layer-0 GEMM (blocks [PB,PB+GB)) ----------------

__global__ __launch_bounds__(256) void part_gemm(
        const int* __restrict__ ei, const int* __restrict__ bhist,
        int* __restrict__ bcur, int2* __restrict__ pairs,
        const unsigned short* __restrict__ Ab, const unsigned short* __restrict__ Wp,
        const float* __restrict__ att_s, const float* __restrict__ att_d,
        unsigned short* __restrict__ Hb, float* __restrict__ asn, float* __restrict__ adn,
        int M) {
    __shared__ float smem[64 * 132];    // 33792 B; partition path aliases ints inside
    int tid = threadIdx.x;
    if (blockIdx.x < PB) {
        unsigned* hist = (unsigned*)smem;             // NBUCK
        unsigned* base = hist + NBUCK;                // NBUCK
        int* bloc = (int*)(base + NBUCK);             // NBUCK
        int* stmp = bloc + NBUCK;                     // 256
        for (int i = tid; i < NBUCK; i += 256) hist[i] = 0;
        scan_bhist(bhist, bloc, stmp);                // barriers inside
        int e0 = blockIdx.x * EPB;
        #pragma unroll
        for (int k = 0; k < EPB / 256; k++) {
            int e = e0 + k * 256 + tid;
            if (e < ET) {
                int d = (e < N_EDGES) ? ei[N_EDGES + e] : (e - N_EDGES);
                atomicAdd(&hist[d >> BSH], 1u);
            }
        }
        __syncthreads();
        for (int i = tid; i < NBUCK; i += 256) {
            unsigned h = hist[i];
            base[i] = h ? (unsigned)(bloc[i] + atomicAdd(&bcur[i], (int)h)) : 0u;
            hist[i] = 0;
        }
        __syncthreads();
        #pragma unroll
        for (int k = 0; k < EPB / 256; k++) {
            int e = e0 + k * 256 + tid;
            if (e < ET) {
                int s, d;
                if (e < N_EDGES) { s = ei[e]; d = ei[N_EDGES + e]; }
                else             { s = d = e - N_EDGES; }
                int bk = d >> BSH;
                unsigned lpos = atomicAdd(&hist[bk], 1u);
                pairs[base[bk] + lpos] = make_int2(s, d);
            }
        }
    } else {
        gemm_attn_body(smem, blockIdx.x - PB, Ab, Wp, att_s, att_d, Hb, asn, adn, M);
    }
}

// ---------------- K3: per bucket (64 nodes), offsets + regroup + fused layer-0 edge weights ----------------

__global__ __launch_bounds__(256) void group_bucket(const int2* __restrict__ pairs,
                                                    const int* __restrict__ bhist,
                                                    int* __restrict__ offs,
                                                    int* __restrict__ ssrc,
                                                    int* __restrict__ sdst,
                                                    const float* __restrict__ asn0,
                                                    const float* __restrict__ adn0,
                                                    float* __restrict__ ew0) {
    __shared__ int bloc[NBUCK];
    __shared__ int stmp[256];
    __shared__ int cnt[64];
    int b = blockIdx.x, tid = threadIdx.x;
    scan_bhist(bhist, bloc, stmp);
    int base = bloc[b];
    int end = (b + 1 < NBUCK) ? bloc[b + 1] : ET;
    int n0 = b << BSH;
    if (tid < 64) cnt[tid] = 0;
    __syncthreads();
    for (int i = base + tid; i < end; i += 256)
        atomicAdd(&cnt[pairs[i].y & 63], 1);
    __syncthreads();
    int v = (tid < 64) ? cnt[tid] : 0;
    stmp[tid] = v;
    __syncthreads();
    for (int off = 1; off < 64; off <<= 1) {
        int x = (tid >= off) ? stmp[tid - off] : 0;
        __syncthreads();
        stmp[tid] += x;
        __syncthreads();
    }
    int excl = stmp[tid] - v;
    if (tid < 64) {
        if (n0 + tid < N_NODES) offs[n0 + tid] = base + excl;
        cnt[tid] = excl;                 // reuse as cursor
    }
    __syncthreads();
    for (int i = base + tid; i < end; i += 256) {
        int2 p = pairs[i];
        int pos = atomicAdd(&cnt[p.y & 63], 1);
        int e = base + pos;
        ssrc[e] = p.x;
        sdst[e] = p.y;
        float4 a = *(const float4*)(asn0 + p.x * 4);
        float4 d = *(const float4*)(adn0 + p.y * 4);
        float4 w;
        w.x = __expf(lrelu(a.x + d.x));
        w.y = __expf(lrelu(a.y + d.y));
        w.z = __expf(lrelu(a.z + d.z));
        w.w = __expf(lrelu(a.w + d.w));
        *(float4*)(ew0 + (size_t)e * 4) = w;
    }
    if (b == 0 && tid == 0) offs[N_NODES] = ET;
}

// ---------------- edge-weight kernels: fully edge-parallel, coalesced output ----------------

__global__ __launch_bounds__(256) void edge_w(
        const int* __restrict__ ssrc, const int* __restrict__ sdst,
        const float* __restrict__ asn, const float* __restrict__ adn,
        float* __restrict__ ew) {
    int e = blockIdx.x * 256 + threadIdx.x;
    if (e >= ET) return;
    int s = ssrc[e], d = sdst[e];
    float4 a = *(const float4*)(asn + s * 4);
    float4 b = *(const float4*)(adn + d * 4);
    float4 w;
    w.x = __expf(lrelu(a.x + b.x));
    w.y = __expf(lrelu(a.y + b.y));
    w.z = __expf(lrelu(a.z + b.z));
    w.w = __expf(lrelu(a.w + b.w));
    *(float4*)(ew + (size_t)e * 4) = w;
}

__global__ __launch_bounds__(256) void edge_w2k(
        const int* __restrict__ ssrc, const int* __restrict__ sdst,
        const float* __restrict__ asn, const float* __restrict__ adn,
        float* __restrict__ ew) {
    int e = blockIdx.x * 256 + threadIdx.x;
    if (e >= ET) return;
    ew[e] = __expf(lrelu(asn[ssrc[e]] + adn[sdst[e]]));
}

// ------- fused K4: aggregate L0 (+bias+BN+ELU) -> LDS bf16 tile -> MFMA GEMM vs W1 -------
// Phase B = coalesced ssrc + ew4 loads only (weights precomputed in group_bucket).

#define AGB 16
#define NAGB (N_NODES / AGB)   // 3125

__global__ __launch_bounds__(256) void agg_gemm1(
        const unsigned short* __restrict__ hb, const float* __restrict__ ew,
        const int* __restrict__ offs, const int* __restrict__ ssrc,
        const float* __restrict__ bias, const float* __restrict__ gamma,
        const float* __restrict__ beta, const float* __restrict__ rmean,
        const float* __restrict__ rvar, const unsigned short* __restrict__ Wp,
        const float* __restrict__ att_s, const float* __restrict__ att_d,
        unsigned short* __restrict__ Hb2, float* __restrict__ asn1,
        float* __restrict__ adn1) {
    __shared__ __attribute__((aligned(16))) unsigned short At[16][136];  // bf16 A tile
    __shared__ __attribute__((aligned(16))) int2 sPair[4][4][72];        // agg phase; reused as ftile
    float* ftile = (float*)&sPair[0][0][0];                              // [16][132]

    int tid = threadIdx.x;
    int wv = tid >> 6, lane = tid & 63;
    int hd = lane >> 4;
    const unsigned short* hlane = hb + 2 * lane;
    const int2* pp = &sPair[wv][hd][0];

    if (lane < 32) sPair[wv][lane >> 3][64 + (lane & 7)] = make_int2(0, 0);

    int c0 = lane * 2;
    float2 bi = *(const float2*)(bias + c0);
    float2 gm = *(const float2*)(gamma + c0);
    float2 bt = *(const float2*)(beta + c0);
    float2 rm = *(const float2*)(rmean + c0);
    float2 rv = *(const float2*)(rvar + c0);
    float sc0 = rsqrtf(rv.x + EPS_BN) * gm.x;
    float sc1 = rsqrtf(rv.y + EPS_BN) * gm.y;

    #pragma unroll 1
    for (int q = 0; q < 4; q++) {
        int lr = wv * 4 + q;
        int node = blockIdx.x * AGB + lr;
        int beg = offs[node], deg = offs[node + 1] - beg;
        float4 den4 = make_float4(0.f, 0.f, 0.f, 0.f);
        float acc0 = 0.f, acc1 = 0.f;

        auto phaseC = [&](int cnt) {
            int bound = (cnt + 7) & ~7;
            for (int i = 0; i < bound; i += 8) {
                int2 p0 = pp[i],     p1 = pp[i + 1], p2 = pp[i + 2], p3 = pp[i + 3];
                int2 p4 = pp[i + 4], p5 = pp[i + 5], p6 = pp[i + 6], p7 = pp[i + 7];
                unsigned u0 = *(const unsigned*)(hlane + (((unsigned)p0.x) << 7));
                unsigned u1 = *(const unsigned*)(hlane + (((unsigned)p1.x) << 7));
                unsigned u2 = *(const unsigned*)(hlane + (((unsigned)p2.x) << 7));
                unsigned u3 = *(const unsigned*)(hlane + (((unsigned)p3.x) << 7));
                unsigned u4 = *(const unsigned*)(hlane + (((unsigned)p4.x) << 7));
                unsigned u5 = *(const unsigned*)(hlane + (((unsigned)p5.x) << 7));
                unsigned u6 = *(const unsigned*)(hlane + (((unsigned)p6.x) << 7));
                unsigned u7 = *(const unsigned*)(hlane + (((unsigned)p7.x) << 7));
                acc0 += __int_as_float(p0.y) * bflo(u0); acc1 += __int_as_float(p0.y) * bfhi(u0);
                acc0 += __int_as_float(p1.y) * bflo(u1); acc1 += __int_as_float(p1.y) * bfhi(u1);
                acc0 += __int_as_float(p2.y) * bflo(u2); acc1 += __int_as_float(p2.y) * bfhi(u2);
                acc0 += __int_as_float(p3.y) * bflo(u3); acc1 += __int_as_float(p3.y) * bfhi(u3);
                acc0 += __int_as_float(p4.y) * bflo(u4); acc1 += __int_as_float(p4.y) * bfhi(u4);
                acc0 += __int_as_float(p5.y) * bflo(u5); acc1 += __int_as_float(p5.y) * bfhi(u5);
                acc0 += __int_as_float(p6.y) * bflo(u6); acc1 += __int_as_float(p6.y) * bfhi(u6);
                acc0 += __int_as_float(p7.y) * bflo(u7); acc1 += __int_as_float(p7.y) * bfhi(u7);
            }
        };

        for (int base0 = 0; base0 < deg; base0 += 64) {
            int j = base0 + lane;
            int s = 0;
            float4 w4 = make_float4(0.f, 0.f, 0.f, 0.f);
            if (j < deg) {
                s = ssrc[beg + j];
                w4 = *(const float4*)(ew + (size_t)(beg + j) * 4);
                den4.x += w4.x; den4.y += w4.y; den4.z += w4.z; den4.w += w4.w;
            }
            sPair[wv][0][lane] = make_int2(s, __float_as_int(w4.x));
            sPair[wv][1][lane] = make_int2(s, __float_as_int(w4.y));
            sPair[wv][2][lane] = make_int2(s, __float_as_int(w4.z));
            sPair[wv][3][lane] = make_int2(s, __float_as_int(w4.w));
            int cnt = deg - base0; if (cnt > 64) cnt = 64;
            phaseC(cnt);
        }

        #pragma unroll
        for (int off = 32; off; off >>= 1) {
            den4.x += __shfl_xor(den4.x, off);
            den4.y += __shfl_xor(den4.y, off);
            den4.z += __shfl_xor(den4.z, off);
            den4.w += __shfl_xor(den4.w, off);
        }
        float den = (hd & 2) ? ((hd & 1) ? den4.w : den4.z)
                             : ((hd & 1) ? den4.y : den4.x);
        float inv = 1.f / (den + 1e-16f);

        float o0 = acc0 * inv + bi.x;
        float o1 = acc1 * inv + bi.y;
        o0 = (o0 - rm.x) * sc0 + bt.x;
        o1 = (o1 - rm.y) * sc1 + bt.y;
        o0 = (o0 > 0.f) ? o0 : expm1f(o0);
        o1 = (o1 > 0.f) ? o1 : expm1f(o1);
        *(unsigned*)&At[lr][c0] = f2bf(o0) | (f2bf(o1) << 16);
    }
    __syncthreads();

    // ---- GEMM: [16 x 128] (At, LDS) @ [128 x 128] (W1 packed) ----
    int koff = hd * 8;
    int ar = lane & 15;
    f32x4 acc2[2];
    acc2[0] = (f32x4){0.f, 0.f, 0.f, 0.f};
    acc2[1] = (f32x4){0.f, 0.f, 0.f, 0.f};
    #pragma unroll
    for (int kc = 0; kc < 4; kc++) {
        short8 a = *(const short8*)&At[ar][kc * 32 + koff];
        #pragma unroll
        for (int ti = 0; ti < 2; ti++) {
            int t = wv * 2 + ti;
            short8 bfr = *(const short8*)(Wp + (((t * 4 + kc) * 64 + lane) << 3));
            acc2[ti] = __builtin_amdgcn_mfma_f32_16x16x32_bf16(a, bfr, acc2[ti], 0, 0, 0);
        }
    }
    __syncthreads();   // all At reads + sPair usage complete

    int rbase = hd * 4;
    int col = lane & 15;
    #pragma unroll
    for (int ti = 0; ti < 2; ti++) {
        int t = wv * 2 + ti;
        #pragma unroll
        for (int r = 0; r < 4; r++)
            ftile[(rbase + r) * 132 + t * 16 + col] = acc2[ti][r];
    }
    __syncthreads();

    {   // bf16 h-store: 16 rows x 16 col-groups = 256 threads, one shot
        int rl = tid >> 4, cg = tid & 15;
        int row = blockIdx.x * AGB + rl;
        const float* p = ftile + rl * 132 + cg * 8;
        float4 v0 = *(const float4*)(p);
        float4 v1 = *(const float4*)(p + 4);
        uint4 o;
        o.x = f2bf(v0.x) | (f2bf(v0.y) << 16);
        o.y = f2bf(v0.z) | (f2bf(v0.w) << 16);
        o.z = f2bf(v1.x) | (f2bf(v1.y) << 16);
        o.w = f2bf(v1.z) | (f2bf(v1.w) << 16);
        *(uint4*)(Hb2 + (size_t)row * 128 + cg * 8) = o;
    }
    if (tid < 64) {   // attn coeffs: 16 rows x 4 heads
        int rl = tid >> 2, h2d = tid & 3;
        int row = blockIdx.x * AGB + rl;
        const float* hrow = ftile + rl * 132 + h2d * 32;
        const float* as = att_s + h2d * 32;
        const float* ad = att_d + h2d * 32;
        float ps = 0.f, pd = 0.f;
        #pragma unroll
        for (int i = 0; i < 8; i++) {
            float4 hv = *(const float4*)(hrow + i * 4);
            float4 sv = *(const float4*)(as + i * 4);
            float4 dv = *(const float4*)(ad + i * 4);
            ps += hv.x * sv.x + hv.y * sv.y + hv.z * sv.z + hv.w * sv.w;
            pd += hv.x * dv.x + hv.y * dv.y + hv.z * dv.z + hv.w * dv.w;
        }
        asn1[row * 4 + h2d] = ps;
        adn1[row * 4 + h2d] = pd;
    }
}

// ------- fused K5: aggregate L1 (+bias+BN+ELU) + in-register W2 matvec (128->8) -------
// R2-proven shape: 1 node/wave, 4 nodes/block. Phase B uses precomputed ew1.

__global__ __launch_bounds__(256) void agg_mv2(
        const unsigned short* __restrict__ hb, const float* __restrict__ ew,
        const int* __restrict__ offs, const int* __restrict__ ssrc,
        const float* __restrict__ bias, const float* __restrict__ gamma,
        const float* __restrict__ beta, const float* __restrict__ rmean,
        const float* __restrict__ rvar, const float* __restrict__ W2,
        const float* __restrict__ as2, const float* __restrict__ ad2,
        float* __restrict__ h2, float* __restrict__ as2n, float* __restrict__ ad2n) {
    __shared__ int2 sPair[4][4][72];
    int wv = threadIdx.x >> 6;
    int node = blockIdx.x * 4 + wv;
    if (node >= N_NODES) return;
    int lane = threadIdx.x & 63;
    int hd = lane >> 4;
    int beg = offs[node], deg = offs[node + 1] - beg;

    if (lane < 32) sPair[wv][lane >> 3][64 + (lane & 7)] = make_int2(0, 0);

    float4 den4 = make_float4(0.f, 0.f, 0.f, 0.f);
    float acc0 = 0.f, acc1 = 0.f;
    const unsigned short* hlane = hb + 2 * lane;
    const int2* pp = &sPair[wv][hd][0];

    auto phaseC = [&](int cnt) {
        int bound = (cnt + 7) & ~7;
        for (int i = 0; i < bound; i += 8) {
            int2 p0 = pp[i],     p1 = pp[i + 1], p2 = pp[i + 2], p3 = pp[i + 3];
            int2 p4 = pp[i + 4], p5 = pp[i + 5], p6 = pp[i + 6], p7 = pp[i + 7];
            unsigned u0 = *(const unsigned*)(hlane + (((unsigned)p0.x) << 7));
            unsigned u1 = *(const unsigned*)(hlane + (((unsigned)p1.x) << 7));
            unsigned u2 = *(const unsigned*)(hlane + (((unsigned)p2.x) << 7));
            unsigned u3 = *(const unsigned*)(hlane + (((unsigned)p3.x) << 7));
            unsigned u4 = *(const unsigned*)(hlane + (((unsigned)p4.x) << 7));
            unsigned u5 = *(const unsigned*)(hlane + (((unsigned)p5.x) << 7));
            unsigned u6 = *(const unsigned*)(hlane + (((unsigned)p6.x) << 7));
            unsigned u7 = *(const unsigned*)(hlane + (((unsigned)p7.x) << 7));
            acc0 += __int_as_float(p0.y) * bflo(u0); acc1 += __int_as_float(p0.y) * bfhi(u0);
            acc0 += __int_as_float(p1.y) * bflo(u1); acc1 += __int_as_float(p1.y) * bfhi(u1);
            acc0 += __int_as_float(p2.y) * bflo(u2); acc1 += __int_as_float(p2.y) * bfhi(u2);
            acc0 += __int_as_float(p3.y) * bflo(u3); acc1 += __int_as_float(p3.y) * bfhi(u3);
            acc0 += __int_as_float(p4.y) * bflo(u4); acc1 += __int_as_float(p4.y) * bfhi(u4);
            acc0 += __int_as_float(p5.y) * bflo(u5); acc1 += __int_as_float(p5.y) * bfhi(u5);
            acc0 += __int_as_float(p6.y) * bflo(u6); acc1 += __int_as_float(p6.y) * bfhi(u6);
            acc0 += __int_as_float(p7.y) * bflo(u7); acc1 += __int_as_float(p7.y) * bfhi(u7);
        }
    };

    for (int base0 = 0; base0 < deg; base0 += 64) {
        int j = base0 + lane;
        int s = 0;
        float4 w4 = make_float4(0.f, 0.f, 0.f, 0.f);
        if (j < deg) {
            s = ssrc[beg + j];
            w4 = *(const float4*)(ew + (size_t)(beg + j) * 4);
            den4.x += w4.x; den4.y += w4.y; den4.z += w4.z; den4.w += w4.w;
        }
        sPair[wv][0][lane] = make_int2(s, __float_as_int(w4.x));
        sPair[wv][1][lane] = make_int2(s, __float_as_int(w4.y));
        sPair[wv][2][lane] = make_int2(s, __float_as_int(w4.z));
        sPair[wv][3][lane] = make_int2(s, __float_as_int(w4.w));
        int cnt = deg - base0; if (cnt > 64) cnt = 64;
        phaseC(cnt);
    }

    #pragma unroll
    for (int off = 32; off; off >>= 1) {
        den4.x += __shfl_xor(den4.x, off);
        den4.y += __shfl_xor(den4.y, off);
        den4.z += __shfl_xor(den4.z, off);
        den4.w += __shfl_xor(den4.w, off);
    }
    float den = (hd & 2) ? ((hd & 1) ? den4.w : den4.z)
                         : ((hd & 1) ? den4.y : den4.x);
    float inv = 1.f / (den + 1e-16f);

    int c0 = lane * 2;
    float2 bi = *(const float2*)(bias + c0);
    float2 gm = *(const float2*)(gamma + c0);
    float2 bt = *(const float2*)(beta + c0);
    float2 rm = *(const float2*)(rmean + c0);
    float2 rv = *(const float2*)(rvar + c0);
    float o0 = acc0 * inv + bi.x;
    float o1 = acc1 * inv + bi.y;
    o0 = (o0 - rm.x) * rsqrtf(rv.x + EPS_BN) * gm.x + bt.x;
    o1 = (o1 - rm.y) * rsqrtf(rv.y + EPS_BN) * gm.y + bt.y;
    o0 = (o0 > 0.f) ? o0 : expm1f(o0);
    o1 = (o1 > 0.f) ? o1 : expm1f(o1);

    // in-register matvec: t8[c] = sum_k elu_out[k] * W2[k][c], per-lane partial then reduce
    const float4* w2r = (const float4*)(W2 + c0 * 8);
    float4 wa0 = w2r[0], wa1 = w2r[1], wb0 = w2r[2], wb1 = w2r[3];
    float t8[8];
    t8[0] = o0 * wa0.x + o1 * wb0.x;
    t8[1] = o0 * wa0.y + o1 * wb0.y;
    t8[2] = o0 * wa0.z + o1 * wb0.z;
    t8[3] = o0 * wa0.w + o1 * wb0.w;
    t8[4] = o0 * wa1.x + o1 * wb1.x;
    t8[5] = o0 * wa1.y + o1 * wb1.y;
    t8[6] = o0 * wa1.z + o1 * wb1.z;
    t8[7] = o0 * wa1.w + o1 * wb1.w;
    #pragma unroll
    for (int off = 32; off; off >>= 1)
        #pragma unroll
        for (int c = 0; c < 8; c++) t8[c] += __shfl_xor(t8[c], off);
    if (lane == 0) {
        float ps = 0.f, pd = 0.f;
        #pragma unroll
        for (int c = 0; c < 8; c++) {
            h2[(size_t)node * 8 + c] = t8[c];
            ps += t8[c] * as2[c];
            pd += t8[c] * ad2[c];
        }
        as2n[node] = ps;
        ad2n[node] = pd;
    }
}

// ------- layer 2 aggregation + bias + log_softmax: one wave/node (precomputed ew2) -------

__global__ __launch_bounds__(256) void aggregate2(
        const float* __restrict__ h2, const float* __restrict__ ew2,
        const int* __restrict__ offs, const int* __restrict__ ssrc,
        const float* __restrict__ b2, float* __restrict__ out) {
    __shared__ int2 sPair[4][64];
    int wv = threadIdx.x >> 6;
    int node = blockIdx.x * 4 + wv;
    if (node >= N_NODES) return;
    int lane = threadIdx.x & 63;
    int g = lane >> 3, c = lane & 7;
    int beg = offs[node], end = offs[node + 1];
    int deg = end - beg;

    float den = 0.f, acc = 0.f;
    auto phaseC = [&](int cnt) {
        int nIt = (cnt + 15) >> 4;
        const int2* pp = &sPair[wv][0];
        for (int i = 0; i < nIt; i++) {
            int e = i * 16 + g;
            int2 p0 = pp[e];
            int2 p1 = pp[e + 8];
            acc += __int_as_float(p0.y) * h2[(((unsigned)p0.x) << 3) + c];
            acc += __int_as_float(p1.y) * h2[(((unsigned)p1.x) << 3) + c];
        }
    };

    for (int base = 0; base < deg; base += 64) {
        int j = base + lane;
        int s = 0; float w = 0.f;
        if (j < deg) {
            s = ssrc[beg + j];
            w = ew2[beg + j];
            den += w;
        }
        sPair[wv][lane] = make_int2(s, __float_as_int(w));
        int cnt = deg - base; if (cnt > 64) cnt = 64;
        phaseC(cnt);
    }

    acc += __shfl_xor(acc, 8); acc += __shfl_xor(acc, 16); acc += __shfl_xor(acc, 32);
    #pragma unroll
    for (int off = 32; off; off >>= 1) den += __shfl_xor(den, off);

    float o = acc / (den + 1e-16f) + b2[c];
    float mx = o;
    mx = fmaxf(mx, __shfl_xor(mx, 1));
    mx = fmaxf(mx, __shfl_xor(mx, 2));
    mx = fmaxf(mx, __shfl_xor(mx, 4));
    float ex = __expf(o - mx);
    float sm = ex;
    sm += __shfl_xor(sm, 1); sm += __shfl_xor(sm, 2); sm += __shfl_xor(sm, 4);
    if (g == 0) out[(size_t)node * 8 + c] = o - mx - logf(sm);
}

// ---------------- launch ----------------

extern "C" void kernel_launch(void* const* d_in, const int* in_sizes, int n_in,
                              void* d_out, int out_size, void* d_ws, size_t ws_size,
                              hipStream_t stream) {
    const float* x   = (const float*)d_in[0];
    const int*   ei  = (const int*)d_in[1];
    const float* W0  = (const float*)d_in[2];
    const float* as0 = (const float*)d_in[3];
    const float* ad0 = (const float*)d_in[4];
    const float* b0  = (const float*)d_in[5];
    const float* g0  = (const float*)d_in[6];
    const float* bb0 = (const float*)d_in[7];
    const float* rm0 = (const float*)d_in[8];
    const float* rv0 = (const float*)d_in[9];
    const float* W1  = (const float*)d_in[10];
    const float* as1 = (const float*)d_in[11];
    const float* ad1 = (const float*)d_in[12];
    const float* b1  = (const float*)d_in[13];
    const float* g1  = (const float*)d_in[14];
    const float* bb1 = (const float*)d_in[15];
    const float* rm1 = (const float*)d_in[16];
    const float* rv1 = (const float*)d_in[17];
    const float* W2  = (const float*)d_in[18];
    const float* as2 = (const float*)d_in[19];
    const float* ad2 = (const float*)d_in[20];
    const float* b2  = (const float*)d_in[21];
    float* out = (float*)d_out;

    char* w = (char*)d_ws;
    size_t off = 0;
    auto carve = [&](size_t bytes) {
        void* p = w + off;
        off += (bytes + 255) & ~(size_t)255;
        return p;
    };
    unsigned short* xb   = (unsigned short*)carve((size_t)N_NODES * 128 * 2);
    unsigned short* Hb   = (unsigned short*)carve((size_t)N_NODES * 128 * 2);
    unsigned short* Hb2  = (unsigned short*)carve((size_t)N_NODES * 128 * 2);
    unsigned short* W0p  = (unsigned short*)carve(16384 * 2);
    unsigned short* W1p  = (unsigned short*)carve(16384 * 2);
    int*   offs   = (int*)carve((size_t)(N_NODES + 1) * 4);
    int*   bhist  = (int*)carve((size_t)NBUCK * 2 * 4);   // bhist + bcur (one memset)
    int*   bcur   = bhist + NBUCK;
    int*   ssrc   = (int*)carve((size_t)ET * 4);
    int*   sdst   = (int*)carve((size_t)ET * 4);
    float* ewf    = (float*)carve((size_t)ET * 4 * 4);    // shared: ew0 -> ew1 -> ew2
    int2*  pairs  = (int2*)carve((size_t)ET * 8);
    float* asn0   = (float*)carve((size_t)N_NODES * 4 * 4);
    float* adn0   = (float*)carve((size_t)N_NODES * 4 * 4);
    float* asn1   = (float*)carve((size_t)N_NODES * 4 * 4);
    float* adn1   = (float*)carve((size_t)N_NODES * 4 * 4);
    float* h2     = (float*)carve((size_t)N_NODES * 8 * 4);
    float* as2n   = (float*)carve((size_t)N_NODES * 4);
    float* ad2n   = (float*)carve((size_t)N_NODES * 4);
    (void)ws_size; (void)in_sizes; (void)n_in; (void)out_size;

    const int GB = (N_NODES + 63) / 64;
    const int EB = (ET + 255) / 256;

    hipMemsetAsync(bhist, 0, (size_t)NBUCK * 2 * 4, stream);
    // K1: cast + weight-pack + bucket histogram (independent work fused)
    prep_hist<<<CAST_B + 2 * PACK_B + PB, 256, 0, stream>>>(x, xb, W0, W0p, W1, W1p, ei, bhist);
    // K2: radix partition (needs bhist) || layer-0 GEMM (needs xb/W0p) — fused, overlap
    part_gemm<<<PB + GB, 256, 0, stream>>>(ei, bhist, bcur, pairs,
                                           xb, W0p, as0, ad0, Hb, asn0, adn0, N_NODES);
    // K3: per-bucket grouping + fused layer-0 edge weights
    group_bucket<<<NBUCK, 256, 0, stream>>>(pairs, bhist, offs, ssrc, sdst,
                                            asn0, adn0, ewf);
    // K4: aggregate L0 + BN/ELU -> LDS tile -> GEMM W1 (ew0-driven phase B)
    agg_gemm1<<<NAGB, 256, 0, stream>>>(Hb, ewf, offs, ssrc,
                                        b0, g0, bb0, rm0, rv0,
                                        W1p, as1, ad1, Hb2, asn1, adn1);
    // edge weights for layer 1 (overwrites ewf)
    edge_w<<<EB, 256, 0, stream>>>(ssrc, sdst, asn1, adn1, ewf);
    // K5: aggregate L1 + BN/ELU + W2 matvec (R2 shape, ew1-driven phase B)
    agg_mv2<<<(N_NODES + 3) / 4, 256, 0, stream>>>(Hb2, ewf, offs, ssrc,
                                                   b1, g1, bb1, rm1, rv1,
                                                   W2, as2, ad2, h2, as2n, ad2n);
    // edge weights for layer 2 (scalar, overwrites ewf)
    edge_w2k<<<EB, 256, 0, stream>>>(ssrc, sdst, as2n, ad2n, ewf);
    // K6: layer-2 aggregation + log_softmax
    aggregate2<<<(N_NODES + 3) / 4, 256, 0, stream>>>(h2, ewf, offs, ssrc, b2, out);
}

// Round 7
// 273.824 us; speedup vs baseline: 1.0763x; 1.0763x over previous
//
#include <hip/hip_runtime.h>
#include <math.h>

#define N_NODES 50000
#define N_EDGES 800000
#define ET (N_EDGES + N_NODES)   // with self-loops
#define FDIM 128
#define HEADS 4
#define HID 32
#define NCLS 8
#define NEG 0.2f
#define EPS_BN 1e-5f

#define BSH 6                                   // 64 nodes per bucket
#define NBUCK ((N_NODES + 63) >> BSH)           // 782
#define EPB 4096                                // edges per partition block

typedef __attribute__((ext_vector_type(8))) short short8;
typedef __attribute__((ext_vector_type(4))) float f32x4;

__device__ __forceinline__ float lrelu(float e) { return e > 0.f ? e : NEG * e; }
__device__ __forceinline__ float bflo(unsigned u) { return __uint_as_float(u << 16); }
__device__ __forceinline__ float bfhi(unsigned u) { return __uint_as_float(u & 0xffff0000u); }
__device__ __forceinline__ unsigned f2bf(float f) {           // RNE round to bf16 bits
    unsigned b = __float_as_uint(f);
    return (b + 0x7fffu + ((b >> 16) & 1u)) >> 16;
}

// exclusive scan of bhist[NBUCK] into bloc[NBUCK] using stmp[256]; all 256 threads.
__device__ __forceinline__ void scan_bhist(const int* __restrict__ bhist,
                                           int* bloc, int* stmp) {
    int t = threadIdx.x;
    int idx = t * 4;
    int v0 = (idx     < NBUCK) ? bhist[idx]     : 0;
    int v1 = (idx + 1 < NBUCK) ? bhist[idx + 1] : 0;
    int v2 = (idx + 2 < NBUCK) ? bhist[idx + 2] : 0;
    int v3 = (idx + 3 < NBUCK) ? bhist[idx + 3] : 0;
    int sum = v0 + v1 + v2 + v3;
    stmp[t] = sum;
    __syncthreads();
    for (int off = 1; off < 256; off <<= 1) {
        int x = (t >= off) ? stmp[t - off] : 0;
        __syncthreads();
        stmp[t] += x;
        __syncthreads();
    }
    int run = stmp[t] - sum;
    if (idx     < NBUCK) bloc[idx]     = run; run += v0;
    if (idx + 1 < NBUCK) bloc[idx + 1] = run; run += v1;
    if (idx + 2 < NBUCK) bloc[idx + 2] = run; run += v2;
    if (idx + 3 < NBUCK) bloc[idx + 3] = run;
    __syncthreads();
}

// ---------------- fused K1: x->bf16 cast + W0/W1 fragment packing + bucket histogram ----------------

#define CAST_B 3125   // 50000*128/8/256
#define PACK_B 64     // 16384/256
#define PB ((ET + EPB - 1) / EPB)   // 208

__global__ __launch_bounds__(256) void prep_hist(
        const float* __restrict__ x, unsigned short* __restrict__ xb,
        const float* __restrict__ W0, unsigned short* __restrict__ W0p,
        const float* __restrict__ W1, unsigned short* __restrict__ W1p,
        const int* __restrict__ ei, int* __restrict__ bhist) {
    __shared__ unsigned h[NBUCK];
    int b = blockIdx.x, tid = threadIdx.x;
    if (b < CAST_B) {
        int i = b * 256 + tid;
        const float4* p = (const float4*)x + (size_t)i * 2;
        float4 a = p[0], c = p[1];
        uint4 o;
        o.x = f2bf(a.x) | (f2bf(a.y) << 16);
        o.y = f2bf(a.z) | (f2bf(a.w) << 16);
        o.z = f2bf(c.x) | (f2bf(c.y) << 16);
        o.w = f2bf(c.z) | (f2bf(c.w) << 16);
        ((uint4*)xb)[i] = o;
    } else if (b < CAST_B + 2 * PACK_B) {
        int pb = b - CAST_B;
        const float* W = (pb < PACK_B) ? W0 : W1;
        unsigned short* Wp = (pb < PACK_B) ? W0p : W1p;
        int o = (pb & (PACK_B - 1)) * 256 + tid;
        int j = o & 7, lane = (o >> 3) & 63, kc = (o >> 9) & 3, t = o >> 11;
        int k = kc * 32 + ((lane >> 4) << 3) + j;
        int n = t * 16 + (lane & 15);
        Wp[o] = (unsigned short)f2bf(W[k * 128 + n]);
    } else {
        int blk = b - (CAST_B + 2 * PACK_B);
        int e0 = blk * EPB;
        for (int i = tid; i < NBUCK; i += 256) h[i] = 0;
        __syncthreads();
        #pragma unroll
        for (int k = 0; k < EPB / 256; k++) {
            int e = e0 + k * 256 + tid;
            if (e < ET) {
                int d = (e < N_EDGES) ? ei[N_EDGES + e] : (e - N_EDGES);
                atomicAdd(&h[d >> BSH], 1u);
            }
        }
        __syncthreads();
        for (int i = tid; i < NBUCK; i += 256)
            if (h[i]) atomicAdd(&bhist[i], (int)h[i]);
    }
}

// ------- shared gemm body: fused MFMA GEMM (64 x 128 @ 128 x 128) + bf16 h-store + attn coeffs -------

__device__ __forceinline__ void gemm_attn_body(
        float* tiles, int gb,
        const unsigned short* __restrict__ Ab, const unsigned short* __restrict__ Wp,
        const float* __restrict__ att_s, const float* __restrict__ att_d,
        unsigned short* __restrict__ Hb, float* __restrict__ asn, float* __restrict__ adn,
        int M) {
    int tid = threadIdx.x;
    int wv = tid >> 6, lane = tid & 63;
    int base = gb * 64;
    int mrow = base + wv * 16 + (lane & 15);
    if (mrow >= M) mrow = M - 1;
    int koff = (lane >> 4) * 8;

    f32x4 acc[8];
    #pragma unroll
    for (int t = 0; t < 8; t++) acc[t] = (f32x4){0.f, 0.f, 0.f, 0.f};

    #pragma unroll
    for (int kc = 0; kc < 4; kc++) {
        short8 a = *(const short8*)(Ab + (size_t)mrow * 128 + kc * 32 + koff);
        #pragma unroll
        for (int t = 0; t < 8; t++) {
            short8 bfr = *(const short8*)(Wp + (((t * 4 + kc) * 64 + lane) << 3));
            acc[t] = __builtin_amdgcn_mfma_f32_16x16x32_bf16(a, bfr, acc[t], 0, 0, 0);
        }
    }

    int rbase = wv * 16 + (lane >> 4) * 4;
    int col = lane & 15;
    #pragma unroll
    for (int t = 0; t < 8; t++)
        #pragma unroll
        for (int r = 0; r < 4; r++)
            tiles[(rbase + r) * 132 + t * 16 + col] = acc[t][r];
    __syncthreads();

    #pragma unroll
    for (int it = 0; it < 4; it++) {
        int u = tid + it * 256;
        int rl = u >> 4, cg = u & 15;
        int row = base + rl;
        if (row < M) {
            const float* p = tiles + rl * 132 + cg * 8;
            float4 v0 = *(const float4*)(p);
            float4 v1 = *(const float4*)(p + 4);
            uint4 o;
            o.x = f2bf(v0.x) | (f2bf(v0.y) << 16);
            o.y = f2bf(v0.z) | (f2bf(v0.w) << 16);
            o.z = f2bf(v1.x) | (f2bf(v1.y) << 16);
            o.w = f2bf(v1.z) | (f2bf(v1.w) << 16);
            *(uint4*)(Hb + (size_t)row * 128 + cg * 8) = o;
        }
    }

    {
        int rl = tid >> 2, hd = tid & 3;
        int row = base + rl;
        if (row < M) {
            const float* hrow = tiles + rl * 132 + hd * 32;
            const float* as = att_s + hd * 32;
            const float* ad = att_d + hd * 32;
            float ps = 0.f, pd = 0.f;
            #pragma unroll
            for (int i = 0; i < 8; i++) {
                float4 hv = *(const float4*)(hrow + i * 4);
                float4 sv = *(const float4*)(as + i * 4);
                float4 dv = *(const float4*)(ad + i * 4);
                ps += hv.x * sv.x + hv.y * sv.y + hv.z * sv.z + hv.w * sv.w;
                pd += hv.x * dv.x + hv.y * dv.y + hv.z * dv.z + hv.w * dv.w;
            }
            asn[row * 4 + hd] = ps;
            adn[row * 4 + hd] = pd;
        }
    }
}

// ---------------- fused K2: radix partition (blocks [0,PB)) + layer-0 GEMM (blocks [PB,PB+GB)) ----------------

__global__ __launch_bounds__(256) void part_gemm(
        const int* __restrict__ ei, const int* __restrict__ bhist,
        int* __restrict__ bcur, int2* __restrict__ pairs,
        const unsigned short* __restrict__ Ab, const unsigned short* __restrict__ Wp,
        const float* __restrict__ att_s, const float* __restrict__ att_d,
        unsigned short* __restrict__ Hb, float* __restrict__ asn, float* __restrict__ adn,
        int M) {
    __shared__ float smem[64 * 132];    // 33792 B; partition path aliases ints inside
    int tid = threadIdx.x;
    if (blockIdx.x < PB) {
        unsigned* hist = (unsigned*)smem;             // NBUCK
        unsigned* base = hist + NBUCK;                // NBUCK
        int* bloc = (int*)(base + NBUCK);             // NBUCK
        int* stmp = bloc + NBUCK;                     // 256
        for (int i = tid; i < NBUCK; i += 256) hist[i] = 0;
        scan_bhist(bhist, bloc, stmp);                // barriers inside
        int e0 = blockIdx.x * EPB;
        #pragma unroll
        for (int k = 0; k < EPB / 256; k++) {
            int e = e0 + k * 256 + tid;
            if (e < ET) {
                int d = (e < N_EDGES) ? ei[N_EDGES + e] : (e - N_EDGES);
                atomicAdd(&hist[d >> BSH], 1u);
            }
        }
        __syncthreads();
        for (int i = tid; i < NBUCK; i += 256) {
            unsigned h = hist[i];
            base[i] = h ? (unsigned)(bloc[i] + atomicAdd(&bcur[i], (int)h)) : 0u;
            hist[i] = 0;
        }
        __syncthreads();
        #pragma unroll
        for (int k = 0; k < EPB / 256; k++) {
            int e = e0 + k * 256 + tid;
            if (e < ET) {
                int s, d;
                if (e < N_EDGES) { s = ei[e]; d = ei[N_EDGES + e]; }
                else             { s = d = e - N_EDGES; }
                int bk = d >> BSH;
                unsigned lpos = atomicAdd(&hist[bk], 1u);
                pairs[base[bk] + lpos] = make_int2(s, d);
            }
        }
    } else {
        gemm_attn_body(smem, blockIdx.x - PB, Ab, Wp, att_s, att_d, Hb, asn, adn, M);
    }
}

// ---------------- K3: per bucket (64 nodes), per-node offsets + regroup pairs -> ssrc ----------------

__global__ __launch_bounds__(256) void group_bucket(const int2* __restrict__ pairs,
                                                    const int* __restrict__ bhist,
                                                    int* __restrict__ offs,
                                                    int* __restrict__ ssrc) {
    __shared__ int bloc[NBUCK];
    __shared__ int stmp[256];
    __shared__ int cnt[64];
    int b = blockIdx.x, tid = threadIdx.x;
    scan_bhist(bhist, bloc, stmp);
    int base = bloc[b];
    int end = (b + 1 < NBUCK) ? bloc[b + 1] : ET;
    int n0 = b << BSH;
    if (tid < 64) cnt[tid] = 0;
    __syncthreads();
    for (int i = base + tid; i < end; i += 256)
        atomicAdd(&cnt[pairs[i].y & 63], 1);
    __syncthreads();
    int v = (tid < 64) ? cnt[tid] : 0;
    stmp[tid] = v;
    __syncthreads();
    for (int off = 1; off < 64; off <<= 1) {
        int x = (tid >= off) ? stmp[tid - off] : 0;
        __syncthreads();
        stmp[tid] += x;
        __syncthreads();
    }
    int excl = stmp[tid] - v;
    if (tid < 64) {
        if (n0 + tid < N_NODES) offs[n0 + tid] = base + excl;
        cnt[tid] = excl;                 // reuse as cursor
    }
    __syncthreads();
    for (int i = base + tid; i < end; i += 256) {
        int2 p = pairs[i];
        int pos = atomicAdd(&cnt[p.y & 63], 1);
        ssrc[base + pos] = p.x;
    }
    if (b == 0 && tid == 0) offs[N_NODES] = ET;
}

// ------- scalar-index gather core -------
// Gather index s is wave-uniform per edge: load it via the SCALAR path (readfirstlane'd
// base -> s_load), compute the row base on the SALU, and issue the row read as
// global_load with SGPR base + constant per-lane voffset. LDS carries only the 4
// head-weight planes (stride 68 -> heads on distinct banks; reads broadcast).

#define PHASE_C_8(swv, hlane, hd, cnt, ebase, i, acc0, acc1)                          \
    {                                                                                 \
        _Pragma("unroll")                                                             \
        for (int k = 0; k < 8; k++) {                                                 \
            int e_ = (i) + k;                                                         \
            int sk_ = (e_ < (cnt)) ? ssrc[(ebase) + e_] : 0;                          \
            unsigned uk_ = *(const unsigned*)((hlane) + ((size_t)(unsigned)sk_ << 7));\
            float wk_ = swv[(hd) * 68 + e_];                                          \
            acc0 += wk_ * bflo(uk_);                                                  \
            acc1 += wk_ * bfhi(uk_);                                                  \
        }                                                                             \
    }

// ------- fused K4: aggregate L0 (+bias+BN+ELU) -> LDS bf16 tile -> MFMA GEMM vs W1 -------
// 16 nodes per block, 4 waves x 4 nodes sequential (R2-proven shape), scalar-index gather.

#define AGB 16
#define NAGB (N_NODES / AGB)   // 3125

__global__ __launch_bounds__(256) void agg_gemm1(
        const unsigned short* __restrict__ hb, const float* __restrict__ asn,
        const float* __restrict__ adn, const int* __restrict__ offs,
        const int* __restrict__ ssrc, const float* __restrict__ bias,
        const float* __restrict__ gamma, const float* __restrict__ beta,
        const float* __restrict__ rmean, const float* __restrict__ rvar,
        const unsigned short* __restrict__ Wp,
        const float* __restrict__ att_s, const float* __restrict__ att_d,
        unsigned short* __restrict__ Hb2, float* __restrict__ asn1,
        float* __restrict__ adn1) {
    __shared__ __attribute__((aligned(16))) unsigned short At[16][136];  // bf16 A tile
    __shared__ __attribute__((aligned(16))) float fbuf[16 * 132];        // ftile; aliases sW planes
    float* ftile = fbuf;

    int tid = threadIdx.x;
    int wv = tid >> 6, lane = tid & 63;
    int hd = lane >> 4;
    const unsigned short* hlane = hb + 2 * lane;
    float* swv = fbuf + wv * 4 * 68;          // [4 planes][68] per wave (4352B total)

    int c0 = lane * 2;
    float2 bi = *(const float2*)(bias + c0);
    float2 gm = *(const float2*)(gamma + c0);
    float2 bt = *(const float2*)(beta + c0);
    float2 rm = *(const float2*)(rmean + c0);
    float2 rv = *(const float2*)(rvar + c0);
    float sc0 = rsqrtf(rv.x + EPS_BN) * gm.x;
    float sc1 = rsqrtf(rv.y + EPS_BN) * gm.y;

    #pragma unroll 1
    for (int q = 0; q < 4; q++) {
        int lr = wv * 4 + q;
        int node = blockIdx.x * AGB + lr;
        int begu = __builtin_amdgcn_readfirstlane(offs[node]);
        int degu = __builtin_amdgcn_readfirstlane(offs[node + 1]) - begu;
        float4 ad4 = *(const float4*)(adn + node * 4);
        float4 den4 = make_float4(0.f, 0.f, 0.f, 0.f);
        float acc0 = 0.f, acc1 = 0.f;

        for (int base0 = 0; base0 < degu; base0 += 64) {
            int j = base0 + lane;
            float4 w4 = make_float4(0.f, 0.f, 0.f, 0.f);
            if (j < degu) {
                int s = ssrc[begu + j];
                float4 a = *(const float4*)(asn + s * 4);
                w4.x = __expf(lrelu(a.x + ad4.x));
                w4.y = __expf(lrelu(a.y + ad4.y));
                w4.z = __expf(lrelu(a.z + ad4.z));
                w4.w = __expf(lrelu(a.w + ad4.w));
                den4.x += w4.x; den4.y += w4.y; den4.z += w4.z; den4.w += w4.w;
            }
            swv[0 * 68 + lane] = w4.x;
            swv[1 * 68 + lane] = w4.y;
            swv[2 * 68 + lane] = w4.z;
            swv[3 * 68 + lane] = w4.w;
            int cnt = degu - base0; if (cnt > 64) cnt = 64;
            int bound = (cnt + 7) & ~7;
            int ebase = begu + base0;
            for (int i = 0; i < bound; i += 8)
                PHASE_C_8(swv, hlane, hd, cnt, ebase, i, acc0, acc1);
        }

        #pragma unroll
        for (int off = 32; off; off >>= 1) {
            den4.x += __shfl_xor(den4.x, off);
            den4.y += __shfl_xor(den4.y, off);
            den4.z += __shfl_xor(den4.z, off);
            den4.w += __shfl_xor(den4.w, off);
        }
        float den = (hd & 2) ? ((hd & 1) ? den4.w : den4.z)
                             : ((hd & 1) ? den4.y : den4.x);
        float inv = 1.f / (den + 1e-16f);

        float o0 = acc0 * inv + bi.x;
        float o1 = acc1 * inv + bi.y;
        o0 = (o0 - rm.x) * sc0 + bt.x;
        o1 = (o1 - rm.y) * sc1 + bt.y;
        o0 = (o0 > 0.f) ? o0 : expm1f(o0);
        o1 = (o1 > 0.f) ? o1 : expm1f(o1);
        *(unsigned*)&At[lr][c0] = f2bf(o0) | (f2bf(o1) << 16);
    }
    __syncthreads();

    // ---- GEMM: [16 x 128] (At, LDS) @ [128 x 128] (W1 packed) ----
    int koff = hd * 8;
    int ar = lane & 15;
    f32x4 acc2[2];
    acc2[0] = (f32x4){0.f, 0.f, 0.f, 0.f};
    acc2[1] = (f32x4){0.f, 0.f, 0.f, 0.f};
    #pragma unroll
    for (int kc = 0; kc < 4; kc++) {
        short8 a = *(const short8*)&At[ar][kc * 32 + koff];
        #pragma unroll
        for (int ti = 0; ti < 2; ti++) {
            int t = wv * 2 + ti;
            short8 bfr = *(const short8*)(Wp + (((t * 4 + kc) * 64 + lane) << 3));
            acc2[ti] = __builtin_amdgcn_mfma_f32_16x16x32_bf16(a, bfr, acc2[ti], 0, 0, 0);
        }
    }
    __syncthreads();   // all At reads + sW usage complete

    int rbase = hd * 4;
    int col = lane & 15;
    #pragma unroll
    for (int ti = 0; ti < 2; ti++) {
        int t = wv * 2 + ti;
        #pragma unroll
        for (int r = 0; r < 4; r++)
            ftile[(rbase + r) * 132 + t * 16 + col] = acc2[ti][r];
    }
    __syncthreads();

    {   // bf16 h-store: 16 rows x 16 col-groups = 256 threads, one shot
        int rl = tid >> 4, cg = tid & 15;
        int row = blockIdx.x * AGB + rl;
        const float* p = ftile + rl * 132 + cg * 8;
        float4 v0 = *(const float4*)(p);
        float4 v1 = *(const float4*)(p + 4);
        uint4 o;
        o.x = f2bf(v0.x) | (f2bf(v0.y) << 16);
        o.y = f2bf(v0.z) | (f2bf(v0.w) << 16);
        o.z = f2bf(v1.x) | (f2bf(v1.y) << 16);
        o.w = f2bf(v1.z) | (f2bf(v1.w) << 16);
        *(uint4*)(Hb2 + (size_t)row * 128 + cg * 8) = o;
    }
    if (tid < 64) {   // attn coeffs: 16 rows x 4 heads
        int rl = tid >> 2, h2d = tid & 3;
        int row = blockIdx.x * AGB + rl;
        const float* hrow = ftile + rl * 132 + h2d * 32;
        const float* as = att_s + h2d * 32;
        const float* ad = att_d + h2d * 32;
        float ps = 0.f, pd = 0.f;
        #pragma unroll
        for (int i = 0; i < 8; i++) {
            float4 hv = *(const float4*)(hrow + i * 4);
            float4 sv = *(const float4*)(as + i * 4);
            float4 dv = *(const float4*)(ad + i * 4);
            ps += hv.x * sv.x + hv.y * sv.y + hv.z * sv.z + hv.w * sv.w;
            pd += hv.x * dv.x + hv.y * dv.y + hv.z * dv.z + hv.w * dv.w;
        }
        asn1[row * 4 + h2d] = ps;
        adn1[row * 4 + h2d] = pd;
    }
}

// ------- fused K5: aggregate L1 (+bias+BN+ELU) + in-register W2 matvec (128->8) -------
// R2-proven shape (1 node/wave, 4 nodes/block) + scalar-index gather.

__global__ __launch_bounds__(256) void agg_mv2(
        const unsigned short* __restrict__ hb, const float* __restrict__ asn,
        const float* __restrict__ adn, const int* __restrict__ offs,
        const int* __restrict__ ssrc, const float* __restrict__ bias,
        const float* __restrict__ gamma, const float* __restrict__ beta,
        const float* __restrict__ rmean, const float* __restrict__ rvar,
        const float* __restrict__ W2, const float* __restrict__ as2,
        const float* __restrict__ ad2, float* __restrict__ h2,
        float* __restrict__ as2n, float* __restrict__ ad2n) {
    __shared__ float sW[4][4 * 68];
    int wv = threadIdx.x >> 6;
    int node = blockIdx.x * 4 + wv;
    if (node >= N_NODES) return;
    int lane = threadIdx.x & 63;
    int hd = lane >> 4;
    int begu = __builtin_amdgcn_readfirstlane(offs[node]);
    int degu = __builtin_amdgcn_readfirstlane(offs[node + 1]) - begu;
    float4 ad4 = *(const float4*)(adn + node * 4);

    float4 den4 = make_float4(0.f, 0.f, 0.f, 0.f);
    float acc0 = 0.f, acc1 = 0.f;
    const unsigned short* hlane = hb + 2 * lane;
    float* swv = sW[wv];

    for (int base0 = 0; base0 < degu; base0 += 64) {
        int j = base0 + lane;
        float4 w4 = make_float4(0.f, 0.f, 0.f, 0.f);
        if (j < degu) {
            int s = ssrc[begu + j];
            float4 a = *(const float4*)(asn + s * 4);
            w4.x = __expf(lrelu(a.x + ad4.x));
            w4.y = __expf(lrelu(a.y + ad4.y));
            w4.z = __expf(lrelu(a.z + ad4.z));
            w4.w = __expf(lrelu(a.w + ad4.w));
            den4.x += w4.x; den4.y += w4.y; den4.z += w4.z; den4.w += w4.w;
        }
        swv[0 * 68 + lane] = w4.x;
        swv[1 * 68 + lane] = w4.y;
        swv[2 * 68 + lane] = w4.z;
        swv[3 * 68 + lane] = w4.w;
        int cnt = degu - base0; if (cnt > 64) cnt = 64;
        int bound = (cnt + 7) & ~7;
        int ebase = begu + base0;
        for (int i = 0; i < bound; i += 8)
            PHASE_C_8(swv, hlane, hd, cnt, ebase, i, acc0, acc1);
    }

    #pragma unroll
    for (int off = 32; off; off >>= 1) {
        den4.x += __shfl_xor(den4.x, off);
        den4.y += __shfl_xor(den4.y, off);
        den4.z += __shfl_xor(den4.z, off);
        den4.w += __shfl_xor(den4.w, off);
    }
    float den = (hd & 2) ? ((hd & 1) ? den4.w : den4.z)
                         : ((hd & 1) ? den4.y : den4.x);
    float inv = 1.f / (den + 1e-16f);

    int c0 = lane * 2;
    float2 bi = *(const float2*)(bias + c0);
    float2 gm = *(const float2*)(gamma + c0);
    float2 bt = *(const float2*)(beta + c0);
    float2 rm = *(const float2*)(rmean + c0);
    float2 rv = *(const float2*)(rvar + c0);
    float o0 = acc0 * inv + bi.x;
    float o1 = acc1 * inv + bi.y;
    o0 = (o0 - rm.x) * rsqrtf(rv.x + EPS_BN) * gm.x + bt.x;
    o1 = (o1 - rm.y) * rsqrtf(rv.y + EPS_BN) * gm.y + bt.y;
    o0 = (o0 > 0.f) ? o0 : expm1f(o0);
    o1 = (o1 > 0.f) ? o1 : expm1f(o1);

    // in-register matvec: t8[c] = sum_k elu_out[k] * W2[k][c], per-lane partial then reduce
    const float4* w2r = (const float4*)(W2 + c0 * 8);
    float4 wa0 = w2r[0], wa1 = w2r[1], wb0 = w2r[2], wb1 = w2r[3];
    float t8[8];
    t8[0] = o0 * wa0.x + o1 * wb0.x;
    t8[1] = o0 * wa0.y + o1 * wb0.y;
    t8[2] = o0 * wa0.z + o1 * wb0.z;
    t8[3] = o0 * wa0.w + o1 * wb0.w;
    t8[4] = o0 * wa1.x + o1 * wb1.x;
    t8[5] = o0 * wa1.y + o1 * wb1.y;
    t8[6] = o0 * wa1.z + o1 * wb1.z;
    t8[7] = o0 * wa1.w + o1 * wb1.w;
    #pragma unroll
    for (int off = 32; off; off >>= 1)
        #pragma unroll
        for (int c = 0; c < 8; c++) t8[c] += __shfl_xor(t8[c], off);
    if (lane == 0) {
        float ps = 0.f, pd = 0.f;
        #pragma unroll
        for (int c = 0; c < 8; c++) {
            h2[(size_t)node * 8 + c] = t8[c];
            ps += t8[c] * as2[c];
            pd += t8[c] * ad2[c];
        }
        as2n[node] = ps;
        ad2n[node] = pd;
    }
}

// ------- layer 2 aggregation + bias + log_softmax: one wave/node (no max pass) -------

__global__ __launch_bounds__(256) void aggregate2(
        const float* __restrict__ h2, const float* __restrict__ asn,
        const float* __restrict__ adn, const int* __restrict__ offs,
        const int* __restrict__ ssrc, const float* __restrict__ b2,
        float* __restrict__ out) {
    __shared__ int2 sPair[4][64];
    int wv = threadIdx.x >> 6;
    int node = blockIdx.x * 4 + wv;
    if (node >= N_NODES) return;
    int lane = threadIdx.x & 63;
    int g = lane >> 3, c = lane & 7;
    int beg = offs[node], end = offs[node + 1];
    int deg = end - beg;
    float adv = adn[node];

    float den = 0.f, acc = 0.f;
    auto phaseC = [&](int cnt) {
        int nIt = (cnt + 15) >> 4;
        const int2* pp = &sPair[wv][0];
        for (int i = 0; i < nIt; i++) {
            int e = i * 16 + g;
            int2 p0 = pp[e];
            int2 p1 = pp[e + 8];
            acc += __int_as_float(p0.y) * h2[(((unsigned)p0.x) << 3) + c];
            acc += __int_as_float(p1.y) * h2[(((unsigned)p1.x) << 3) + c];
        }
    };

    for (int base = 0; base < deg; base += 64) {
        int j = base + lane;
        int s = 0; float w = 0.f;
        if (j < deg) {
            s = ssrc[beg + j];
            w = __expf(lrelu(asn[s] + adv));
            den += w;
        }
        sPair[wv][lane] = make_int2(s, __float_as_int(w));
        int cnt = deg - base; if (cnt > 64) cnt = 64;
        phaseC(cnt);
    }

    acc += __shfl_xor(acc, 8); acc += __shfl_xor(acc, 16); acc += __shfl_xor(acc, 32);
    #pragma unroll
    for (int off = 32; off; off >>= 1) den += __shfl_xor(den, off);

    float o = acc / (den + 1e-16f) + b2[c];
    float mx = o;
    mx = fmaxf(mx, __shfl_xor(mx, 1));
    mx = fmaxf(mx, __shfl_xor(mx, 2));
    mx = fmaxf(mx, __shfl_xor(mx, 4));
    float ex = __expf(o - mx);
    float sm = ex;
    sm += __shfl_xor(sm, 1); sm += __shfl_xor(sm, 2); sm += __shfl_xor(sm, 4);
    if (g == 0) out[(size_t)node * 8 + c] = o - mx - logf(sm);
}

// ---------------- launch ----------------

extern "C" void kernel_launch(void* const* d_in, const int* in_sizes, int n_in,
                              void* d_out, int out_size, void* d_ws, size_t ws_size,
                              hipStream_t stream) {
    const float* x   = (const float*)d_in[0];
    const int*   ei  = (const int*)d_in[1];
    const float* W0  = (const float*)d_in[2];
    const float* as0 = (const float*)d_in[3];
    const float* ad0 = (const float*)d_in[4];
    const float* b0  = (const float*)d_in[5];
    const float* g0  = (const float*)d_in[6];
    const float* bb0 = (const float*)d_in[7];
    const float* rm0 = (const float*)d_in[8];
    const float* rv0 = (const float*)d_in[9];
    const float* W1  = (const float*)d_in[10];
    const float* as1 = (const float*)d_in[11];
    const float* ad1 = (const float*)d_in[12];
    const float* b1  = (const float*)d_in[13];
    const float* g1  = (const float*)d_in[14];
    const float* bb1 = (const float*)d_in[15];
    const float* rm1 = (const float*)d_in[16];
    const float* rv1 = (const float*)d_in[17];
    const float* W2  = (const float*)d_in[18];
    const float* as2 = (const float*)d_in[19];
    const float* ad2 = (const float*)d_in[20];
    const float* b2  = (const float*)d_in[21];
    float* out = (float*)d_out;

    char* w = (char*)d_ws;
    size_t off = 0;
    auto carve = [&](size_t bytes) {
        void* p = w + off;
        off += (bytes + 255) & ~(size_t)255;
        return p;
    };
    unsigned short* xb   = (unsigned short*)carve((size_t)N_NODES * 128 * 2);
    unsigned short* Hb   = (unsigned short*)carve((size_t)N_NODES * 128 * 2);
    unsigned short* Hb2  = (unsigned short*)carve((size_t)N_NODES * 128 * 2);
    unsigned short* W0p  = (unsigned short*)carve(16384 * 2);
    unsigned short* W1p  = (unsigned short*)carve(16384 * 2);
    int*   offs   = (int*)carve((size_t)(N_NODES + 1) * 4);
    int*   bhist  = (int*)carve((size_t)NBUCK * 2 * 4);   // bhist + bcur (one memset)
    int*   bcur   = bhist + NBUCK;
    int*   ssrc   = (int*)carve((size_t)ET * 4);
    int2*  pairs  = (int2*)carve((size_t)ET * 8);
    float* asn0   = (float*)carve((size_t)N_NODES * 4 * 4);
    float* adn0   = (float*)carve((size_t)N_NODES * 4 * 4);
    float* asn1   = (float*)carve((size_t)N_NODES * 4 * 4);
    float* adn1   = (float*)carve((size_t)N_NODES * 4 * 4);
    float* h2     = (float*)carve((size_t)N_NODES * 8 * 4);
    float* as2n   = (float*)carve((size_t)N_NODES * 4);
    float* ad2n   = (float*)carve((size_t)N_NODES * 4);
    (void)ws_size; (void)in_sizes; (void)n_in; (void)out_size;

    const int GB = (N_NODES + 63) / 64;

    hipMemsetAsync(bhist, 0, (size_t)NBUCK * 2 * 4, stream);
    // K1: cast + weight-pack + bucket histogram (independent work fused)
    prep_hist<<<CAST_B + 2 * PACK_B + PB, 256, 0, stream>>>(x, xb, W0, W0p, W1, W1p, ei, bhist);
    // K2: radix partition (needs bhist) || layer-0 GEMM (needs xb/W0p) — fused, overlap
    part_gemm<<<PB + GB, 256, 0, stream>>>(ei, bhist, bcur, pairs,
                                           xb, W0p, as0, ad0, Hb, asn0, adn0, N_NODES);
    // K3: per-bucket grouping (64-node buckets -> 782 blocks)
    group_bucket<<<NBUCK, 256, 0, stream>>>(pairs, bhist, offs, ssrc);
    // K4: aggregate L0 + BN/ELU -> LDS tile -> GEMM W1 (scalar-index gather)
    agg_gemm1<<<NAGB, 256, 0, stream>>>(Hb, asn0, adn0, offs, ssrc,
                                        b0, g0, bb0, rm0, rv0,
                                        W1p, as1, ad1, Hb2, asn1, adn1);
    // K5: aggregate L1 + BN/ELU + W2 matvec (scalar-index gather)
    agg_mv2<<<(N_NODES + 3) / 4, 256, 0, stream>>>(Hb2, asn1, adn1, offs, ssrc,
                                                   b1, g1, bb1, rm1, rv1,
                                                   W2, as2, ad2, h2, as2n, ad2n);
    // K6: layer-2 aggregation + log_softmax
    aggregate2<<<(N_NODES + 3) / 4, 256, 0, stream>>>(h2, as2n, ad2n, offs, ssrc, b2, out);
}